// Round 13
// baseline (174.437 us; speedup 1.0000x reference)
//
#include <hip/hip_runtime.h>

// SelfAttention: B=4, S=2048, D=1024, fp32 in/out. bf16 MFMA, fp32 accum.
// R12: R11 (32x32x16 MFMA core2) + subtile-parity XOR swizzle fix.
// R11's regression was SQ_LDS_BANK_CONFLICT 0 -> 3.1M: 32x32 frag reads pair
// half-waves onto adjacent 1024B subtiles at the SAME byte offset (1024 % 128
// == 0 -> same banks). Fix: XOR bit-5 of the intra-subtile byte offset with
// subtile parity on BOTH store (pre-swizzled global source) and read sides.
// Wave's four 16-lane clusters then read offsets {0,32,16,48} -- the pattern
// measured conflict-free in R7-R10.
//   qkproj: core2 GEOM0 256x256, grid (32,8) = 256 blocks (Q and K)
//   vproj:  core2 GEOM1 128x256, grid (64,4) = 256 blocks (Vt transposed)
//   sc:     core2 GEOM0, grid (8,8,4) = 256, P~=exp(QK^T/32)+rowsums
//   pv:     core2 GEOM1, grid (16,4,4) = 256, * 1/rowsum (in-kernel rsum)
// ws layout (MiB):
//   [0,16)   x_bf16 (proj) -> P~ bf16 [4][2048][2048]
//   [16,32)  Q bf16   [32,48) K bf16   [48,64) Vt bf16 [4][1024][2048]
//   [64,70)  Wq|Wk|Wv bf16
//   [70,+256K) rowpart fp32 [8][4][2048]

typedef __bf16 bf16x8 __attribute__((ext_vector_type(8)));
typedef float f32x16 __attribute__((ext_vector_type(16)));
typedef unsigned short u16;

__device__ __forceinline__ u16 f2b(float f) {
  union { float f; unsigned u; } a; a.f = f;
  unsigned r = a.u + 0x7fffu + ((a.u >> 16) & 1u);  // RNE
  return (u16)(r >> 16);
}

// blocks [0,8192): x (2097152 float4s). blocks [8192,11264): Wq|Wk|Wv.
__global__ __launch_bounds__(256) void cast_all_kernel(const float* __restrict__ x,
                                                       const float* __restrict__ Wq,
                                                       const float* __restrict__ Wk,
                                                       const float* __restrict__ Wv,
                                                       u16* __restrict__ xb,
                                                       u16* __restrict__ Wb) {
  int b = blockIdx.x;
  if (b < 8192) {
    const int i = b * 256 + threadIdx.x;
    float4 v = reinterpret_cast<const float4*>(x)[i];
    reinterpret_cast<ushort4*>(xb)[i] =
        make_ushort4(f2b(v.x), f2b(v.y), f2b(v.z), f2b(v.w));
  } else {
    b -= 8192;
    const int w = b >> 10;
    const float* src = (w == 0) ? Wq : (w == 1) ? Wk : Wv;
    const int i = (b & 1023) * 256 + threadIdx.x;
    float4 v = reinterpret_cast<const float4*>(src)[i];
    reinterpret_cast<ushort4*>(Wb + (size_t)w * 1048576)[i] =
        make_ushort4(f2b(v.x), f2b(v.y), f2b(v.z), f2b(v.w));
  }
}

// ---------------- merged-phase double-buffered core, 32x32x16 MFMA (R12) ----------------
// GEOM 0: BM=256,BN=256, acc f32x16[8] (4 mi x 2 ni); GEOM 1: BM=128,BN=256, acc f32x16[4].
// 8 waves: wr=wave>>2 (M), wc=wave&3 (N); wave tile GEOM0 128x64, GEOM1 64x64.
// BK=64 (2 halves x 2 ksteps of 16). Staging/vmcnt/barriers = R7 core2, unchanged.
// LDS mapping (per 1024B subtile c): physical P holds logical
//   L = P ^ ((P>>9 & 1)<<5) ^ ((c & 1)<<5)   [row-swizzle + subtile-parity swizzle]
template <int GEOM, int NT>
__device__ __forceinline__ void core2(const char* __restrict__ Ab,
                                      const char* __restrict__ Bb, int lda, int ldb,
                                      char* smem, f32x16* acc) {
  constexpr int LDSBUF = GEOM ? 49152 : 65536;
  constexpr int BOFF = GEOM ? 16384 : 32768;
  constexpr int AHALF = GEOM ? 8192 : 16384;
  constexpr int NMI = GEOM ? 2 : 4;  // 32-row A subtiles per wave
  const int tid = threadIdx.x;
  const int wave = tid >> 6, lane = tid & 63;
  const int wr = wave >> 2, wc = wave & 3;
  const int hi16 = (lane >> 4) & 1;
  // read base: row=lane&15 in 16-row subtile, k16-group=(lane>>5); row-swizzle bit5
  const int rdbase = (((lane & 15) * 64 + (lane >> 5) * 16)) ^ (((lane >> 3) & 1) << 5);
  // staging source logical byte: lane*16, row-swizzle, + subtile-parity (wave&1)
  const int li = (lane * 16) ^ ((lane >> 5) << 5) ^ ((wave & 1) << 5);
  const int sr = li >> 6, sc2 = li & 63;

  auto STAGE = [&](int kt, int s) {  // A-half s + B-half s of tile kt
    char* base = smem + (kt & 1) * LDSBUF;
    const int colOff = kt * 128 + s * 64 + sc2;
    char* ldsA = base + s * AHALF;
    __builtin_amdgcn_global_load_lds(
        (const __attribute__((address_space(1))) void*)(Ab + (size_t)(wave * 16 + sr) * lda + colOff),
        (__attribute__((address_space(3))) void*)(ldsA + wave * 1024), 16, 0, 0);
    if constexpr (GEOM == 0)
      __builtin_amdgcn_global_load_lds(  // subtile 8+wave: same parity as wave
          (const __attribute__((address_space(1))) void*)(Ab + (size_t)((8 + wave) * 16 + sr) * lda + colOff),
          (__attribute__((address_space(3))) void*)(ldsA + 8192 + wave * 1024), 16, 0, 0);
    char* ldsB = base + BOFF + s * 16384;
    __builtin_amdgcn_global_load_lds(
        (const __attribute__((address_space(1))) void*)(Bb + (size_t)(wave * 16 + sr) * ldb + colOff),
        (__attribute__((address_space(3))) void*)(ldsB + wave * 1024), 16, 0, 0);
    __builtin_amdgcn_global_load_lds(
        (const __attribute__((address_space(1))) void*)(Bb + (size_t)((8 + wave) * 16 + sr) * ldb + colOff),
        (__attribute__((address_space(3))) void*)(ldsB + 8192 + wave * 1024), 16, 0, 0);
  };

  // prologue: both halves of tile 0; land half 0, keep half 1 in flight
  STAGE(0, 0);
  STAGE(0, 1);
  if constexpr (GEOM == 0) asm volatile("s_waitcnt vmcnt(4)" ::: "memory");
  else asm volatile("s_waitcnt vmcnt(3)" ::: "memory");
  __builtin_amdgcn_s_barrier();
  __builtin_amdgcn_sched_barrier(0);

  for (int kt = 0; kt < NT; ++kt) {
    const char* bufA = smem + (kt & 1) * LDSBUF;
    const char* bufB = bufA + BOFF;
#pragma unroll
    for (int s = 0; s < 2; ++s) {
      bf16x8 afr[2 * NMI], bfr[4];
#pragma unroll
      for (int ks = 0; ks < 2; ++ks) {
#pragma unroll
        for (int mi = 0; mi < NMI; ++mi) {
          const int sub = wr * (GEOM ? 4 : 8) + mi * 2 + hi16;
          const int inner = rdbase ^ (ks << 5) ^ ((sub & 1) << 5);
          afr[ks * NMI + mi] =
              *reinterpret_cast<const bf16x8*>(bufA + s * AHALF + sub * 1024 + inner);
        }
#pragma unroll
        for (int ni = 0; ni < 2; ++ni) {
          const int sub = wc * 4 + ni * 2 + hi16;
          const int inner = rdbase ^ (ks << 5) ^ ((sub & 1) << 5);
          bfr[ks * 2 + ni] =
              *reinterpret_cast<const bf16x8*>(bufB + s * 16384 + sub * 1024 + inner);
        }
      }
      if (kt + 1 < NT) STAGE(kt + 1, s);
      __builtin_amdgcn_s_barrier();
      __builtin_amdgcn_sched_barrier(0);
      __builtin_amdgcn_s_setprio(1);
#pragma unroll
      for (int ks = 0; ks < 2; ++ks)
#pragma unroll
        for (int mi = 0; mi < NMI; ++mi)
#pragma unroll
          for (int ni = 0; ni < 2; ++ni)
            acc[mi * 2 + ni] = __builtin_amdgcn_mfma_f32_32x32x16_bf16(
                afr[ks * NMI + mi], bfr[ks * 2 + ni], acc[mi * 2 + ni], 0, 0, 0);
      __builtin_amdgcn_s_setprio(0);
      if (kt < NT - 1) {
        if constexpr (GEOM == 0) asm volatile("s_waitcnt vmcnt(4)" ::: "memory");
        else asm volatile("s_waitcnt vmcnt(3)" ::: "memory");
      } else if (s == 0) {
        asm volatile("s_waitcnt vmcnt(0)" ::: "memory");
      }
      __builtin_amdgcn_s_barrier();
      __builtin_amdgcn_sched_barrier(0);
    }
  }
}

// C/D row within a 32-row subtile
#define CROW(reg, hi) (((reg) & 3) + 8 * ((reg) >> 2) + 4 * (hi))

// ---------------- QK projection: GEOM0 256x256, grid (32,8) = 256 exact ----------------
__global__ __launch_bounds__(512, 2) void qkproj_kernel(
    const u16* __restrict__ A, const u16* __restrict__ Bm,
    const float* __restrict__ bq, const float* __restrict__ bk,
    u16* __restrict__ QK) {
  extern __shared__ char smem[];
  const int tileM = blockIdx.x * 256, tileN = blockIdx.y * 256;
  f32x16 acc[8] = {};
  core2<0, 16>((const char*)A + (size_t)tileM * 2048,
               (const char*)Bm + (size_t)tileN * 2048, 2048, 2048, smem, acc);
  const int tid = threadIdx.x;
  const int wave = tid >> 6, lane = tid & 63;
  const int wr = wave >> 2, wc = wave & 3, hi = lane >> 5, c31 = lane & 31;
  const int w = blockIdx.y >> 2;  // 0 -> Q, 1 -> K
  const float* bias = (w == 0) ? bq : bk;
  u16* O = QK + (size_t)w * 8388608;
#pragma unroll
  for (int mi = 0; mi < 4; ++mi) {
#pragma unroll
    for (int ni = 0; ni < 2; ++ni) {
      const int cw = (tileN + wc * 64 + ni * 32 + c31) & 1023;
      const float bi = bias[cw];
#pragma unroll
      for (int reg = 0; reg < 16; ++reg) {
        const int row = tileM + wr * 128 + mi * 32 + CROW(reg, hi);
        O[(size_t)row * 1024 + cw] = f2b(acc[mi * 2 + ni][reg] + bi);
      }
    }
  }
}

// ---------------- V projection: GEOM1 128x256, grid (64,4) = 256 exact ----------------
__global__ __launch_bounds__(512, 2) void vproj_kernel(
    const u16* __restrict__ A, const u16* __restrict__ Bv,
    const float* __restrict__ bvv, u16* __restrict__ Vt) {
  extern __shared__ char smem[];
  const int tileM = blockIdx.x * 128, tileN = blockIdx.y * 256;
  f32x16 acc[4] = {};
  core2<1, 16>((const char*)A + (size_t)tileM * 2048,
               (const char*)Bv + (size_t)tileN * 2048, 2048, 2048, smem, acc);
  const int tid = threadIdx.x;
  const int wave = tid >> 6, lane = tid & 63;
  const int wr = wave >> 2, wc = wave & 3, hi = lane >> 5, c31 = lane & 31;
#pragma unroll
  for (int mi = 0; mi < 2; ++mi) {
#pragma unroll
    for (int ni = 0; ni < 2; ++ni) {
      const int cw = (tileN + wc * 64 + ni * 32 + c31) & 1023;
      const float bi = bvv[cw];
#pragma unroll
      for (int q = 0; q < 4; ++q) {
        const int r0 = tileM + wr * 64 + mi * 32 + 8 * q + 4 * hi;  // rows r0..r0+3
        const int b = r0 >> 11, s0 = r0 & 2047;  // 4-aligned, never straddles batch
        ushort4 u = make_ushort4(
            f2b(acc[mi * 2 + ni][q * 4 + 0] + bi), f2b(acc[mi * 2 + ni][q * 4 + 1] + bi),
            f2b(acc[mi * 2 + ni][q * 4 + 2] + bi), f2b(acc[mi * 2 + ni][q * 4 + 3] + bi));
        *reinterpret_cast<ushort4*>(&Vt[(size_t)b * 2097152 + (size_t)cw * 2048 + s0]) = u;
      }
    }
  }
}

// ---------------- sc: P~ = exp(Q K^T / 32) (bf16) + row-sum partials ----------------
__global__ __launch_bounds__(512, 2) void sc8_kernel(const u16* __restrict__ Qb,
                                                     const u16* __restrict__ Kb,
                                                     u16* __restrict__ P,
                                                     float* __restrict__ rowpart) {
  extern __shared__ char smem[];
  const int z = blockIdx.z;
  const int tileM = blockIdx.x * 256, tileN = blockIdx.y * 256;
  f32x16 acc[8] = {};
  core2<0, 16>((const char*)Qb + (size_t)z * 4194304 + (size_t)tileM * 2048,
               (const char*)Kb + (size_t)z * 4194304 + (size_t)tileN * 2048, 2048, 2048,
               smem, acc);
  const int tid = threadIdx.x;
  const int wave = tid >> 6, lane = tid & 63;
  const int wr = wave >> 2, wc = wave & 3, hi = lane >> 5, c31 = lane & 31;
  float* rs = (float*)smem;  // [4][256]; safe: core2 ends with full barrier
  u16* Po = P + (size_t)z * 4194304 + (size_t)tileM * 2048 + tileN;
#pragma unroll
  for (int mi = 0; mi < 4; ++mi) {
#pragma unroll
    for (int reg = 0; reg < 16; ++reg) {
      const int rl = wr * 128 + mi * 32 + CROW(reg, hi);
      const float e0 = __expf(acc[mi * 2 + 0][reg] * 0.03125f);
      const float e1 = __expf(acc[mi * 2 + 1][reg] * 0.03125f);
      Po[(size_t)rl * 2048 + wc * 64 + c31] = f2b(e0);
      Po[(size_t)rl * 2048 + wc * 64 + 32 + c31] = f2b(e1);
      float part = e0 + e1;
      part += __shfl_xor(part, 1);
      part += __shfl_xor(part, 2);
      part += __shfl_xor(part, 4);
      part += __shfl_xor(part, 8);
      part += __shfl_xor(part, 16);
      if (c31 == 0) rs[wc * 256 + rl] = part;  // lanes 0 & 32: different rl
    }
  }
  __syncthreads();
  if (tid < 256) {
    float s = rs[tid] + rs[256 + tid] + rs[512 + tid] + rs[768 + tid];
    rowpart[(size_t)blockIdx.y * 8192 + z * 2048 + tileM + tid] = s;
  }
}

// ---------------- pv: out = (P~ Vt^T) * rowinv (rowinv computed in-kernel) ----------------
__global__ __launch_bounds__(512, 2) void pv8_kernel(const u16* __restrict__ P,
                                                     const u16* __restrict__ Vt,
                                                     const float* __restrict__ rowpart,
                                                     float* __restrict__ out) {
  extern __shared__ char smem[];  // 98304 core + 512 rowinv
  const int z = blockIdx.z;
  const int tileM = blockIdx.x * 128, tileN = blockIdx.y * 256;
  float* rinv = (float*)(smem + 98304);
  const int tid = threadIdx.x;
  if (tid < 128) {
    float s = 0.f;
#pragma unroll
    for (int t = 0; t < 8; ++t) s += rowpart[t * 8192 + z * 2048 + tileM + tid];
    rinv[tid] = 1.0f / s;
  }
  __builtin_amdgcn_sched_barrier(0);  // pin rinv writes before staging
  // core2's first barrier orders the rinv write before epilogue reads.
  f32x16 acc[4] = {};
  core2<1, 32>((const char*)P + (size_t)z * 8388608 + (size_t)tileM * 4096,
               (const char*)Vt + (size_t)z * 4194304 + (size_t)tileN * 4096, 4096, 4096,
               smem, acc);
  const int wave = tid >> 6, lane = tid & 63;
  const int wr = wave >> 2, wc = wave & 3, hi = lane >> 5, c31 = lane & 31;
  float* O = out + (size_t)z * 2097152;
#pragma unroll
  for (int mi = 0; mi < 2; ++mi) {
#pragma unroll
    for (int ni = 0; ni < 2; ++ni) {
#pragma unroll
      for (int reg = 0; reg < 16; ++reg) {
        const int r = wr * 64 + mi * 32 + CROW(reg, hi);
        O[(size_t)(tileM + r) * 1024 + tileN + wc * 64 + ni * 32 + c31] =
            acc[mi * 2 + ni][reg] * rinv[r];
      }
    }
  }
}

extern "C" void kernel_launch(void* const* d_in, const int* in_sizes, int n_in,
                              void* d_out, int out_size, void* d_ws, size_t ws_size,
                              hipStream_t stream) {
  if (ws_size < ((size_t)72 << 20)) return;
  const float* x = (const float*)d_in[0];
  const float* Wq = (const float*)d_in[1];
  const float* bq = (const float*)d_in[2];
  const float* Wk = (const float*)d_in[3];
  const float* bk = (const float*)d_in[4];
  const float* Wv = (const float*)d_in[5];
  const float* bv = (const float*)d_in[6];
  char* ws = (char*)d_ws;
  u16* xb = (u16*)(ws);                       // [0,16M); later P~ [4][2048][2048]
  u16* Pb = (u16*)(ws);
  u16* Qb = (u16*)(ws + ((size_t)16 << 20));
  u16* Kb = (u16*)(ws + ((size_t)32 << 20));
  u16* Vt = (u16*)(ws + ((size_t)48 << 20));
  u16* Wb = (u16*)(ws + ((size_t)64 << 20));
  float* rowpart = (float*)(ws + ((size_t)70 << 20));  // 256 KiB
  float* out = (float*)d_out;

  (void)hipFuncSetAttribute((const void*)qkproj_kernel,
                            hipFuncAttributeMaxDynamicSharedMemorySize, 131072);
  (void)hipFuncSetAttribute((const void*)vproj_kernel,
                            hipFuncAttributeMaxDynamicSharedMemorySize, 98304);
  (void)hipFuncSetAttribute((const void*)sc8_kernel,
                            hipFuncAttributeMaxDynamicSharedMemorySize, 131072);
  (void)hipFuncSetAttribute((const void*)pv8_kernel,
                            hipFuncAttributeMaxDynamicSharedMemorySize, 98816);

  cast_all_kernel<<<11264, 256, 0, stream>>>(x, Wq, Wk, Wv, xb, Wb);

  qkproj_kernel<<<dim3(32, 8), 512, 131072, stream>>>(xb, Wb, bq, bk, Qb);
  vproj_kernel<<<dim3(64, 4), 512, 98304, stream>>>(xb, Wb + 2097152, bv, Vt);

  sc8_kernel<<<dim3(8, 8, 4), 512, 131072, stream>>>(Qb, Kb, Pb, rowpart);
  pv8_kernel<<<dim3(16, 4, 4), 512, 98816, stream>>>(Pb, Vt, rowpart, out);
}

// Round 14
// 156.887 us; speedup vs baseline: 1.1119x; 1.1119x over previous
//
#include <hip/hip_runtime.h>

// SelfAttention: B=4, S=2048, D=1024, fp32 in/out. bf16 MFMA, fp32 accum.
// R13: revert to R10 structure (16x16x32 core2, zero-conflict, 155.9us) +
// T1 XCD-chunked block swizzle on all four GEMMs. R11/R12's 32x32 experiment
// showed identical matrix-pipe cycles (issue-rate hypothesis falsified) plus
// unfixable LDS conflicts -> abandoned. sc8's FETCH=72MB vs 32MB minimal says
// L2 thrash across XCDs; swizzle gives each XCD a contiguous work chunk.
//   qkproj: core2 GEOM0 256x256, 256 blocks (Q and K)
//   vproj:  core2 GEOM1 128x256, 256 blocks (Vt transposed)
//   sc:     core2 GEOM0, 256 blocks, P~=exp(QK^T/32)+rowsums
//   pv:     core2 GEOM1, 256 blocks, * 1/rowsum (in-kernel rsum)
// All grids 1D=256 (=8 XCDs x 32); w = (p&7)*32 + (p>>3) maps dispatch order
// (round-robin over XCDs) to contiguous per-XCD work chunks.
// ws layout (MiB):
//   [0,16)   x_bf16 (proj) -> P~ bf16 [4][2048][2048]
//   [16,32)  Q bf16   [32,48) K bf16   [48,64) Vt bf16 [4][1024][2048]
//   [64,70)  Wq|Wk|Wv bf16
//   [70,+256K) rowpart fp32 [8][4][2048]

typedef __bf16 bf16x8 __attribute__((ext_vector_type(8)));
typedef float f32x4 __attribute__((ext_vector_type(4)));
typedef unsigned short u16;

__device__ __forceinline__ u16 f2b(float f) {
  union { float f; unsigned u; } a; a.f = f;
  unsigned r = a.u + 0x7fffu + ((a.u >> 16) & 1u);  // RNE
  return (u16)(r >> 16);
}

__device__ __forceinline__ int xcd_swz(int p) {  // nwg = 256 (%8 == 0, bijective)
  return (p & 7) * 32 + (p >> 3);
}

// blocks [0,8192): x (2097152 float4s). blocks [8192,11264): Wq|Wk|Wv.
__global__ __launch_bounds__(256) void cast_all_kernel(const float* __restrict__ x,
                                                       const float* __restrict__ Wq,
                                                       const float* __restrict__ Wk,
                                                       const float* __restrict__ Wv,
                                                       u16* __restrict__ xb,
                                                       u16* __restrict__ Wb) {
  int b = blockIdx.x;
  if (b < 8192) {
    const int i = b * 256 + threadIdx.x;
    float4 v = reinterpret_cast<const float4*>(x)[i];
    reinterpret_cast<ushort4*>(xb)[i] =
        make_ushort4(f2b(v.x), f2b(v.y), f2b(v.z), f2b(v.w));
  } else {
    b -= 8192;
    const int w = b >> 10;
    const float* src = (w == 0) ? Wq : (w == 1) ? Wk : Wv;
    const int i = (b & 1023) * 256 + threadIdx.x;
    float4 v = reinterpret_cast<const float4*>(src)[i];
    reinterpret_cast<ushort4*>(Wb + (size_t)w * 1048576)[i] =
        make_ushort4(f2b(v.x), f2b(v.y), f2b(v.z), f2b(v.w));
  }
}

// ---------------- merged-phase double-buffered core (R7/R10, validated) ----------------
// GEOM 0: BM=256,BN=256, acc f32x4[32]; GEOM 1: BM=128,BN=256, acc f32x4[16].
// 8 waves: wr=wave>>2 (M), wc=wave&3 (N). BK=64, NT K-tiles. lda/ldb in BYTES.
template <int GEOM, int NT>
__device__ __forceinline__ void core2(const char* __restrict__ Ab,
                                      const char* __restrict__ Bb, int lda, int ldb,
                                      char* smem, f32x4* acc) {
  constexpr int LDSBUF = GEOM ? 49152 : 65536;
  constexpr int BOFF = GEOM ? 16384 : 32768;
  constexpr int AHALF = GEOM ? 8192 : 16384;
  constexpr int NA = GEOM ? 4 : 8;  // A fragments per phase
  const int tid = threadIdx.x;
  const int wave = tid >> 6, lane = tid & 63;
  const int wr = wave >> 2, wc = wave & 3;
  const int fr = lane & 15, fg = lane >> 4;
  const int rd = (fr * 64 + fg * 16) ^ (((fr >> 3) & 1) << 5);
  const int li = (lane * 16) ^ ((lane >> 5) << 5);
  const int sr = li >> 6, sc2 = li & 63;

  auto STAGE = [&](int kt, int s) {  // A-half s + B-half s of tile kt
    char* base = smem + (kt & 1) * LDSBUF;
    const int colOff = kt * 128 + s * 64 + sc2;
    char* ldsA = base + s * AHALF;
    __builtin_amdgcn_global_load_lds(
        (const __attribute__((address_space(1))) void*)(Ab + (size_t)(wave * 16 + sr) * lda + colOff),
        (__attribute__((address_space(3))) void*)(ldsA + wave * 1024), 16, 0, 0);
    if constexpr (GEOM == 0)
      __builtin_amdgcn_global_load_lds(
          (const __attribute__((address_space(1))) void*)(Ab + (size_t)((8 + wave) * 16 + sr) * lda + colOff),
          (__attribute__((address_space(3))) void*)(ldsA + 8192 + wave * 1024), 16, 0, 0);
    char* ldsB = base + BOFF + s * 16384;
    __builtin_amdgcn_global_load_lds(
        (const __attribute__((address_space(1))) void*)(Bb + (size_t)(wave * 16 + sr) * ldb + colOff),
        (__attribute__((address_space(3))) void*)(ldsB + wave * 1024), 16, 0, 0);
    __builtin_amdgcn_global_load_lds(
        (const __attribute__((address_space(1))) void*)(Bb + (size_t)((8 + wave) * 16 + sr) * ldb + colOff),
        (__attribute__((address_space(3))) void*)(ldsB + 8192 + wave * 1024), 16, 0, 0);
  };

  // prologue: both halves of tile 0; land half 0, keep half 1 in flight
  STAGE(0, 0);
  STAGE(0, 1);
  if constexpr (GEOM == 0) asm volatile("s_waitcnt vmcnt(4)" ::: "memory");
  else asm volatile("s_waitcnt vmcnt(3)" ::: "memory");
  __builtin_amdgcn_s_barrier();
  __builtin_amdgcn_sched_barrier(0);

  for (int kt = 0; kt < NT; ++kt) {
    const char* bufA = smem + (kt & 1) * LDSBUF;
    const char* bufB = bufA + BOFF;
#pragma unroll
    for (int s = 0; s < 2; ++s) {
      bf16x8 afr[NA], bfr[4];
#pragma unroll
      for (int m = 0; m < NA; ++m)
        afr[m] = *reinterpret_cast<const bf16x8*>(bufA + s * AHALF + (wr * NA + m) * 1024 + rd);
#pragma unroll
      for (int n = 0; n < 4; ++n)
        bfr[n] = *reinterpret_cast<const bf16x8*>(bufB + s * 16384 + (wc * 4 + n) * 1024 + rd);
      if (kt + 1 < NT) STAGE(kt + 1, s);
      __builtin_amdgcn_s_barrier();
      __builtin_amdgcn_sched_barrier(0);
      __builtin_amdgcn_s_setprio(1);
#pragma unroll
      for (int m = 0; m < NA; ++m)
#pragma unroll
        for (int n = 0; n < 4; ++n)
          acc[m * 4 + n] = __builtin_amdgcn_mfma_f32_16x16x32_bf16(
              afr[m], bfr[n], acc[m * 4 + n], 0, 0, 0);
      __builtin_amdgcn_s_setprio(0);
      if (kt < NT - 1) {
        if constexpr (GEOM == 0) asm volatile("s_waitcnt vmcnt(4)" ::: "memory");
        else asm volatile("s_waitcnt vmcnt(3)" ::: "memory");
      } else if (s == 0) {
        asm volatile("s_waitcnt vmcnt(0)" ::: "memory");
      }
      __builtin_amdgcn_s_barrier();
      __builtin_amdgcn_sched_barrier(0);
    }
  }
}

// ---------------- QK projection: GEOM0 256x256, 256 blocks (swizzled) ----------------
// A = xb [8192][1024], B = Wb[Wq|Wk] [2048][1024]. w = by>>2: 0 -> Q, 1 -> K.
__global__ __launch_bounds__(512, 2) void qkproj_kernel(
    const u16* __restrict__ A, const u16* __restrict__ Bm,
    const float* __restrict__ bq, const float* __restrict__ bk,
    u16* __restrict__ QK) {
  extern __shared__ char smem[];
  const int wk = xcd_swz(blockIdx.x);
  const int bx = wk & 31, by = wk >> 5;  // (32,8)
  const int tileM = bx * 256, tileN = by * 256;
  f32x4 acc[32] = {};
  core2<0, 16>((const char*)A + (size_t)tileM * 2048,
               (const char*)Bm + (size_t)tileN * 2048, 2048, 2048, smem, acc);
  const int tid = threadIdx.x;
  const int wave = tid >> 6, lane = tid & 63;
  const int wr = wave >> 2, wc = wave & 3, fr = lane & 15, fg = lane >> 4;
  const int w = by >> 2;  // 0 -> Q, 1 -> K (256-col tiles never straddle)
  const float* bias = (w == 0) ? bq : bk;
  u16* O = QK + (size_t)w * 8388608;
#pragma unroll
  for (int mi = 0; mi < 8; ++mi) {
    const int r0 = tileM + wr * 128 + mi * 16 + fg * 4;
#pragma unroll
    for (int n = 0; n < 4; ++n) {
      const int cw = (tileN + wc * 64 + n * 16 + fr) & 1023;
      const float bi = bias[cw];
#pragma unroll
      for (int jj = 0; jj < 4; ++jj)
        O[(size_t)(r0 + jj) * 1024 + cw] = f2b(acc[mi * 4 + n][jj] + bi);
    }
  }
}

// ---------------- V projection: GEOM1 128x256, 256 blocks (swizzled) ----------------
__global__ __launch_bounds__(512, 2) void vproj_kernel(
    const u16* __restrict__ A, const u16* __restrict__ Bv,
    const float* __restrict__ bvv, u16* __restrict__ Vt) {
  extern __shared__ char smem[];
  const int wk = xcd_swz(blockIdx.x);
  const int bx = wk & 63, by = wk >> 6;  // (64,4)
  const int tileM = bx * 128, tileN = by * 256;
  f32x4 acc[16] = {};
  core2<1, 16>((const char*)A + (size_t)tileM * 2048,
               (const char*)Bv + (size_t)tileN * 2048, 2048, 2048, smem, acc);
  const int tid = threadIdx.x;
  const int wave = tid >> 6, lane = tid & 63;
  const int wr = wave >> 2, wc = wave & 3, fr = lane & 15, fg = lane >> 4;
#pragma unroll
  for (int mi = 0; mi < 4; ++mi) {
    const int r0 = tileM + wr * 64 + mi * 16 + fg * 4;
    const int b = r0 >> 11, s0 = r0 & 2047;  // rows r0..r0+3 never straddle a batch
#pragma unroll
    for (int n = 0; n < 4; ++n) {
      const int cw = (tileN + wc * 64 + n * 16 + fr) & 1023;
      const float bi = bvv[cw];
      ushort4 u = make_ushort4(f2b(acc[mi * 4 + n][0] + bi), f2b(acc[mi * 4 + n][1] + bi),
                               f2b(acc[mi * 4 + n][2] + bi), f2b(acc[mi * 4 + n][3] + bi));
      *reinterpret_cast<ushort4*>(&Vt[(size_t)b * 2097152 + (size_t)cw * 2048 + s0]) = u;
    }
  }
}

// ---------------- sc: P~ = exp(Q K^T / 32) (bf16) + row-sum partials ----------------
// 256 blocks (swizzled): decomposed as (bx 8, by 8, z 4); XCD chunk = 4 K-panels.
__global__ __launch_bounds__(512, 2) void sc8_kernel(const u16* __restrict__ Qb,
                                                     const u16* __restrict__ Kb,
                                                     u16* __restrict__ P,
                                                     float* __restrict__ rowpart) {
  extern __shared__ char smem[];
  const int wk = xcd_swz(blockIdx.x);
  const int bx = wk & 7, by = (wk >> 3) & 7, z = wk >> 6;
  const int tileM = bx * 256, tileN = by * 256;
  f32x4 acc[32] = {};
  core2<0, 16>((const char*)Qb + (size_t)z * 4194304 + (size_t)tileM * 2048,
               (const char*)Kb + (size_t)z * 4194304 + (size_t)tileN * 2048, 2048, 2048,
               smem, acc);
  const int tid = threadIdx.x;
  const int wave = tid >> 6, lane = tid & 63;
  const int wr = wave >> 2, wc = wave & 3, fr = lane & 15, fg = lane >> 4;
  float* rs = (float*)smem;  // [4][256]; safe: core2 ends with full barrier
  u16* Po = P + (size_t)z * 4194304 + (size_t)tileM * 2048 + tileN;
#pragma unroll
  for (int mi = 0; mi < 8; ++mi) {
#pragma unroll
    for (int jj = 0; jj < 4; ++jj) {
      const int rl = wr * 128 + mi * 16 + fg * 4 + jj;
      float part = 0.f;
#pragma unroll
      for (int n = 0; n < 4; ++n) {
        float e = __expf(acc[mi * 4 + n][jj] * 0.03125f);
        part += e;
        Po[(size_t)rl * 2048 + wc * 64 + n * 16 + fr] = f2b(e);
      }
      part += __shfl_xor(part, 1);
      part += __shfl_xor(part, 2);
      part += __shfl_xor(part, 4);
      part += __shfl_xor(part, 8);
      if (fr == 0) rs[wc * 256 + rl] = part;
    }
  }
  __syncthreads();
  if (tid < 256) {
    float s = rs[tid] + rs[256 + tid] + rs[512 + tid] + rs[768 + tid];
    rowpart[(size_t)by * 8192 + z * 2048 + tileM + tid] = s;
  }
}

// ---------------- pv: out = (P~ Vt^T) * rowinv (rowinv computed in-kernel) ----------------
// 256 blocks (swizzled): decomposed as (bx 16, by 4, z 4).
__global__ __launch_bounds__(512, 2) void pv8_kernel(const u16* __restrict__ P,
                                                     const u16* __restrict__ Vt,
                                                     const float* __restrict__ rowpart,
                                                     float* __restrict__ out) {
  extern __shared__ char smem[];  // 98304 core + 512 rowinv
  const int wk = xcd_swz(blockIdx.x);
  const int bx = wk & 15, by = (wk >> 4) & 3, z = wk >> 6;
  const int tileM = bx * 128, tileN = by * 256;
  float* rinv = (float*)(smem + 98304);
  const int tid = threadIdx.x;
  if (tid < 128) {
    float s = 0.f;
#pragma unroll
    for (int t = 0; t < 8; ++t) s += rowpart[t * 8192 + z * 2048 + tileM + tid];
    rinv[tid] = 1.0f / s;
  }
  __builtin_amdgcn_sched_barrier(0);  // pin rinv loads/stores before staging
  // core2's first barrier orders the rinv write before epilogue reads.
  f32x4 acc[16] = {};
  core2<1, 32>((const char*)P + (size_t)z * 8388608 + (size_t)tileM * 4096,
               (const char*)Vt + (size_t)z * 4194304 + (size_t)tileN * 4096, 4096, 4096,
               smem, acc);
  const int wave = tid >> 6, lane = tid & 63;
  const int wr = wave >> 2, wc = wave & 3, fr = lane & 15, fg = lane >> 4;
  float* O = out + (size_t)z * 2097152;
#pragma unroll
  for (int mi = 0; mi < 4; ++mi) {
#pragma unroll
    for (int jj = 0; jj < 4; ++jj) {
      const int r = wr * 64 + mi * 16 + fg * 4 + jj;
      const float inv = rinv[r];
#pragma unroll
      for (int n = 0; n < 4; ++n)
        O[(size_t)(tileM + r) * 1024 + tileN + wc * 64 + n * 16 + fr] =
            acc[mi * 4 + n][jj] * inv;
    }
  }
}

extern "C" void kernel_launch(void* const* d_in, const int* in_sizes, int n_in,
                              void* d_out, int out_size, void* d_ws, size_t ws_size,
                              hipStream_t stream) {
  if (ws_size < ((size_t)72 << 20)) return;
  const float* x = (const float*)d_in[0];
  const float* Wq = (const float*)d_in[1];
  const float* bq = (const float*)d_in[2];
  const float* Wk = (const float*)d_in[3];
  const float* bk = (const float*)d_in[4];
  const float* Wv = (const float*)d_in[5];
  const float* bv = (const float*)d_in[6];
  char* ws = (char*)d_ws;
  u16* xb = (u16*)(ws);                       // [0,16M); later P~ [4][2048][2048]
  u16* Pb = (u16*)(ws);
  u16* Qb = (u16*)(ws + ((size_t)16 << 20));
  u16* Kb = (u16*)(ws + ((size_t)32 << 20));
  u16* Vt = (u16*)(ws + ((size_t)48 << 20));
  u16* Wb = (u16*)(ws + ((size_t)64 << 20));
  float* rowpart = (float*)(ws + ((size_t)70 << 20));  // 256 KiB
  float* out = (float*)d_out;

  (void)hipFuncSetAttribute((const void*)qkproj_kernel,
                            hipFuncAttributeMaxDynamicSharedMemorySize, 131072);
  (void)hipFuncSetAttribute((const void*)vproj_kernel,
                            hipFuncAttributeMaxDynamicSharedMemorySize, 98304);
  (void)hipFuncSetAttribute((const void*)sc8_kernel,
                            hipFuncAttributeMaxDynamicSharedMemorySize, 131072);
  (void)hipFuncSetAttribute((const void*)pv8_kernel,
                            hipFuncAttributeMaxDynamicSharedMemorySize, 98816);

  cast_all_kernel<<<11264, 256, 0, stream>>>(x, Wq, Wk, Wv, xb, Wb);

  qkproj_kernel<<<256, 512, 131072, stream>>>(xb, Wb, bq, bk, Qb);
  vproj_kernel<<<256, 512, 98304, stream>>>(xb, Wb + 2097152, bv, Vt);

  sc8_kernel<<<256, 512, 131072, stream>>>(Qb, Kb, Pb, rowpart);
  pv8_kernel<<<256, 512, 98816, stream>>>(Pb, Vt, rowpart, out);
}

// Round 15
// 156.131 us; speedup vs baseline: 1.1172x; 1.0048x over previous
//
#include <hip/hip_runtime.h>

// SelfAttention: B=4, S=2048, D=1024, fp32 in/out. bf16 MFMA, fp32 accum.
// R14: GEOM0 kernels (qkproj, sc8) back on the R4-validated 4-phase deep-
// prefetch core8 (933-952 TF busy measured at R2/R4) -- R10's 2-phase merge
// cost GEOM0 ~20% (777 TF) and was never A/B'd there (R7 tested GEOM1 only).
// GEOM1 kernels (vproj, pv8) keep core2 (4ph vs 2ph null for that shape).
// R13's XCD-chunked swizzle retained on all GEMMs (FETCH 74->25MB, free).
//   qkproj: core8 GEOM0 256x256, 256 blocks (Q and K)
//   vproj:  core2 GEOM1 128x256, 256 blocks (Vt transposed)
//   sc:     core8 GEOM0, 256 blocks, P~=exp(QK^T/32)+rowsums
//   pv:     core2 GEOM1, 256 blocks, * 1/rowsum (in-kernel rsum)
// ws layout (MiB):
//   [0,16)   x_bf16 (proj) -> P~ bf16 [4][2048][2048]
//   [16,32)  Q bf16   [32,48) K bf16   [48,64) Vt bf16 [4][1024][2048]
//   [64,70)  Wq|Wk|Wv bf16
//   [70,+256K) rowpart fp32 [8][4][2048]

typedef __bf16 bf16x8 __attribute__((ext_vector_type(8)));
typedef float f32x4 __attribute__((ext_vector_type(4)));
typedef unsigned short u16;

__device__ __forceinline__ u16 f2b(float f) {
  union { float f; unsigned u; } a; a.f = f;
  unsigned r = a.u + 0x7fffu + ((a.u >> 16) & 1u);  // RNE
  return (u16)(r >> 16);
}

__device__ __forceinline__ int xcd_swz(int p) {  // nwg = 256 (%8 == 0, bijective)
  return (p & 7) * 32 + (p >> 3);
}

// blocks [0,8192): x (2097152 float4s). blocks [8192,11264): Wq|Wk|Wv.
__global__ __launch_bounds__(256) void cast_all_kernel(const float* __restrict__ x,
                                                       const float* __restrict__ Wq,
                                                       const float* __restrict__ Wk,
                                                       const float* __restrict__ Wv,
                                                       u16* __restrict__ xb,
                                                       u16* __restrict__ Wb) {
  int b = blockIdx.x;
  if (b < 8192) {
    const int i = b * 256 + threadIdx.x;
    float4 v = reinterpret_cast<const float4*>(x)[i];
    reinterpret_cast<ushort4*>(xb)[i] =
        make_ushort4(f2b(v.x), f2b(v.y), f2b(v.z), f2b(v.w));
  } else {
    b -= 8192;
    const int w = b >> 10;
    const float* src = (w == 0) ? Wq : (w == 1) ? Wk : Wv;
    const int i = (b & 1023) * 256 + threadIdx.x;
    float4 v = reinterpret_cast<const float4*>(src)[i];
    reinterpret_cast<ushort4*>(Wb + (size_t)w * 1048576)[i] =
        make_ushort4(f2b(v.x), f2b(v.y), f2b(v.z), f2b(v.w));
  }
}

// ---------------- 4-phase deep-prefetch core (R4/R5, validated, GEOM0 here) ----------------
// GEOM 0: BM=256,BN=256, acc f32x4[32]. 8 waves: wr=wave>>2, wc=wave&3.
// BK=64, NT K-tiles, lda/ldb in BYTES. Phase p: s=p>>1 (K-half), j=p&1 (M-half).
// Stage stream: phase g issues S(g+6); steady vmcnt(8) at p1,p3; derived tails.
template <int NT>
__device__ __forceinline__ void core8g0(const char* __restrict__ Ab,
                                        const char* __restrict__ Bb, int lda, int ldb,
                                        char* smem, f32x4* acc) {
  const int tid = threadIdx.x;
  const int wave = tid >> 6, lane = tid & 63;
  const int wr = wave >> 2, wc = wave & 3;
  const int fr = lane & 15, fg = lane >> 4;
  const int rd = (fr * 64 + fg * 16) ^ (((fr >> 3) & 1) << 5);
  const int li = (lane * 16) ^ ((lane >> 5) << 5);
  const int sr = li >> 6, sc2 = li & 63;

  auto STAGE = [&](int kt, int p) {  // half p of tile kt (A or B, one K-half)
    const int isB = p & 1, s = p >> 1;
    char* lds = smem + (kt & 1) * 65536 + (isB ? 32768 + s * 16384 : s * 16384);
    const char* gb = isB ? Bb : Ab;
    const int ldx = isB ? ldb : lda;
    const int colOff = kt * 128 + s * 64 + sc2;
    __builtin_amdgcn_global_load_lds(
        (const __attribute__((address_space(1))) void*)(gb + (size_t)(wave * 16 + sr) * ldx + colOff),
        (__attribute__((address_space(3))) void*)(lds + wave * 1024), 16, 0, 0);
    __builtin_amdgcn_global_load_lds(
        (const __attribute__((address_space(1))) void*)(gb + (size_t)((8 + wave) * 16 + sr) * ldx + colOff),
        (__attribute__((address_space(3))) void*)(lds + 8192 + wave * 1024), 16, 0, 0);
  };

  // prologue: S(0..5) = tile0 all 4 halves + tile1 halves 0,1
#pragma unroll
  for (int p = 0; p < 4; ++p) STAGE(0, p);
  STAGE(1, 0);
  STAGE(1, 1);
  asm volatile("s_waitcnt vmcnt(8)" ::: "memory");
  __builtin_amdgcn_s_barrier();
  __builtin_amdgcn_sched_barrier(0);

  bf16x8 bfr[4];
  for (int kt = 0; kt < NT; ++kt) {
    const char* bufA = smem + (kt & 1) * 65536;
    const char* bufB = bufA + 32768;
#pragma unroll
    for (int p = 0; p < 4; ++p) {
      const int s = p >> 1, j = p & 1;
      bf16x8 afr[4];
      if (j == 0) {
#pragma unroll
        for (int n = 0; n < 4; ++n)
          bfr[n] = *reinterpret_cast<const bf16x8*>(bufB + s * 16384 + (wc * 4 + n) * 1024 + rd);
      }
#pragma unroll
      for (int m = 0; m < 4; ++m)
        afr[m] = *reinterpret_cast<const bf16x8*>(bufA + s * 16384 + (wr * 8 + j * 4 + m) * 1024 + rd);
      if (p < 2) { if (kt + 1 < NT) STAGE(kt + 1, p + 2); }
      else       { if (kt + 2 < NT) STAGE(kt + 2, p - 2); }
      __builtin_amdgcn_s_barrier();
      __builtin_amdgcn_sched_barrier(0);
      __builtin_amdgcn_s_setprio(1);
#pragma unroll
      for (int m = 0; m < 4; ++m)
#pragma unroll
        for (int n = 0; n < 4; ++n)
          acc[(j * 4 + m) * 4 + n] = __builtin_amdgcn_mfma_f32_16x16x32_bf16(
              afr[m], bfr[n], acc[(j * 4 + m) * 4 + n], 0, 0, 0);
      __builtin_amdgcn_s_setprio(0);
      if (p == 1) {
        if (kt < NT - 1) asm volatile("s_waitcnt vmcnt(8)" ::: "memory");
        else asm volatile("s_waitcnt vmcnt(0)" ::: "memory");
      } else if (p == 3) {
        if (kt < NT - 2) asm volatile("s_waitcnt vmcnt(8)" ::: "memory");
        else if (kt == NT - 2) asm volatile("s_waitcnt vmcnt(4)" ::: "memory");
      }
      __builtin_amdgcn_s_barrier();
      __builtin_amdgcn_sched_barrier(0);
    }
  }
}

// ---------------- merged-phase core (GEOM1 kernels; R7/R10 validated) ----------------
// GEOM 1: BM=128,BN=256, acc f32x4[16]. 8 waves. BK=64. lda/ldb in BYTES.
template <int NT>
__device__ __forceinline__ void core2g1(const char* __restrict__ Ab,
                                        const char* __restrict__ Bb, int lda, int ldb,
                                        char* smem, f32x4* acc) {
  const int tid = threadIdx.x;
  const int wave = tid >> 6, lane = tid & 63;
  const int wr = wave >> 2, wc = wave & 3;
  const int fr = lane & 15, fg = lane >> 4;
  const int rd = (fr * 64 + fg * 16) ^ (((fr >> 3) & 1) << 5);
  const int li = (lane * 16) ^ ((lane >> 5) << 5);
  const int sr = li >> 6, sc2 = li & 63;

  auto STAGE = [&](int kt, int s) {  // A-half s + B-half s of tile kt (3 loads)
    char* base = smem + (kt & 1) * 49152;
    const int colOff = kt * 128 + s * 64 + sc2;
    char* ldsA = base + s * 8192;
    __builtin_amdgcn_global_load_lds(
        (const __attribute__((address_space(1))) void*)(Ab + (size_t)(wave * 16 + sr) * lda + colOff),
        (__attribute__((address_space(3))) void*)(ldsA + wave * 1024), 16, 0, 0);
    char* ldsB = base + 16384 + s * 16384;
    __builtin_amdgcn_global_load_lds(
        (const __attribute__((address_space(1))) void*)(Bb + (size_t)(wave * 16 + sr) * ldb + colOff),
        (__attribute__((address_space(3))) void*)(ldsB + wave * 1024), 16, 0, 0);
    __builtin_amdgcn_global_load_lds(
        (const __attribute__((address_space(1))) void*)(Bb + (size_t)((8 + wave) * 16 + sr) * ldb + colOff),
        (__attribute__((address_space(3))) void*)(ldsB + 8192 + wave * 1024), 16, 0, 0);
  };

  STAGE(0, 0);
  STAGE(0, 1);
  asm volatile("s_waitcnt vmcnt(3)" ::: "memory");
  __builtin_amdgcn_s_barrier();
  __builtin_amdgcn_sched_barrier(0);

  for (int kt = 0; kt < NT; ++kt) {
    const char* bufA = smem + (kt & 1) * 49152;
    const char* bufB = bufA + 16384;
#pragma unroll
    for (int s = 0; s < 2; ++s) {
      bf16x8 afr[4], bfr[4];
#pragma unroll
      for (int m = 0; m < 4; ++m)
        afr[m] = *reinterpret_cast<const bf16x8*>(bufA + s * 8192 + (wr * 4 + m) * 1024 + rd);
#pragma unroll
      for (int n = 0; n < 4; ++n)
        bfr[n] = *reinterpret_cast<const bf16x8*>(bufB + s * 16384 + (wc * 4 + n) * 1024 + rd);
      if (kt + 1 < NT) STAGE(kt + 1, s);
      __builtin_amdgcn_s_barrier();
      __builtin_amdgcn_sched_barrier(0);
      __builtin_amdgcn_s_setprio(1);
#pragma unroll
      for (int m = 0; m < 4; ++m)
#pragma unroll
        for (int n = 0; n < 4; ++n)
          acc[m * 4 + n] = __builtin_amdgcn_mfma_f32_16x16x32_bf16(
              afr[m], bfr[n], acc[m * 4 + n], 0, 0, 0);
      __builtin_amdgcn_s_setprio(0);
      if (kt < NT - 1) {
        asm volatile("s_waitcnt vmcnt(3)" ::: "memory");
      } else if (s == 0) {
        asm volatile("s_waitcnt vmcnt(0)" ::: "memory");
      }
      __builtin_amdgcn_s_barrier();
      __builtin_amdgcn_sched_barrier(0);
    }
  }
}

// ---------------- QK projection: core8g0 256x256, 256 blocks (swizzled) ----------------
__global__ __launch_bounds__(512, 2) void qkproj_kernel(
    const u16* __restrict__ A, const u16* __restrict__ Bm,
    const float* __restrict__ bq, const float* __restrict__ bk,
    u16* __restrict__ QK) {
  extern __shared__ char smem[];
  const int wk = xcd_swz(blockIdx.x);
  const int bx = wk & 31, by = wk >> 5;  // (32,8)
  const int tileM = bx * 256, tileN = by * 256;
  f32x4 acc[32] = {};
  core8g0<16>((const char*)A + (size_t)tileM * 2048,
              (const char*)Bm + (size_t)tileN * 2048, 2048, 2048, smem, acc);
  const int tid = threadIdx.x;
  const int wave = tid >> 6, lane = tid & 63;
  const int wr = wave >> 2, wc = wave & 3, fr = lane & 15, fg = lane >> 4;
  const int w = by >> 2;  // 0 -> Q, 1 -> K
  const float* bias = (w == 0) ? bq : bk;
  u16* O = QK + (size_t)w * 8388608;
#pragma unroll
  for (int mi = 0; mi < 8; ++mi) {
    const int r0 = tileM + wr * 128 + mi * 16 + fg * 4;
#pragma unroll
    for (int n = 0; n < 4; ++n) {
      const int cw = (tileN + wc * 64 + n * 16 + fr) & 1023;
      const float bi = bias[cw];
#pragma unroll
      for (int jj = 0; jj < 4; ++jj)
        O[(size_t)(r0 + jj) * 1024 + cw] = f2b(acc[mi * 4 + n][jj] + bi);
    }
  }
}

// ---------------- V projection: core2g1 128x256, 256 blocks (swizzled) ----------------
__global__ __launch_bounds__(512, 2) void vproj_kernel(
    const u16* __restrict__ A, const u16* __restrict__ Bv,
    const float* __restrict__ bvv, u16* __restrict__ Vt) {
  extern __shared__ char smem[];
  const int wk = xcd_swz(blockIdx.x);
  const int bx = wk & 63, by = wk >> 6;  // (64,4)
  const int tileM = bx * 128, tileN = by * 256;
  f32x4 acc[16] = {};
  core2g1<16>((const char*)A + (size_t)tileM * 2048,
              (const char*)Bv + (size_t)tileN * 2048, 2048, 2048, smem, acc);
  const int tid = threadIdx.x;
  const int wave = tid >> 6, lane = tid & 63;
  const int wr = wave >> 2, wc = wave & 3, fr = lane & 15, fg = lane >> 4;
#pragma unroll
  for (int mi = 0; mi < 4; ++mi) {
    const int r0 = tileM + wr * 64 + mi * 16 + fg * 4;
    const int b = r0 >> 11, s0 = r0 & 2047;
#pragma unroll
    for (int n = 0; n < 4; ++n) {
      const int cw = (tileN + wc * 64 + n * 16 + fr) & 1023;
      const float bi = bvv[cw];
      ushort4 u = make_ushort4(f2b(acc[mi * 4 + n][0] + bi), f2b(acc[mi * 4 + n][1] + bi),
                               f2b(acc[mi * 4 + n][2] + bi), f2b(acc[mi * 4 + n][3] + bi));
      *reinterpret_cast<ushort4*>(&Vt[(size_t)b * 2097152 + (size_t)cw * 2048 + s0]) = u;
    }
  }
}

// ---------------- sc: core8g0; P~ = exp(Q K^T / 32) (bf16) + row-sum partials ----------------
__global__ __launch_bounds__(512, 2) void sc8_kernel(const u16* __restrict__ Qb,
                                                     const u16* __restrict__ Kb,
                                                     u16* __restrict__ P,
                                                     float* __restrict__ rowpart) {
  extern __shared__ char smem[];
  const int wk = xcd_swz(blockIdx.x);
  const int bx = wk & 7, by = (wk >> 3) & 7, z = wk >> 6;
  const int tileM = bx * 256, tileN = by * 256;
  f32x4 acc[32] = {};
  core8g0<16>((const char*)Qb + (size_t)z * 4194304 + (size_t)tileM * 2048,
              (const char*)Kb + (size_t)z * 4194304 + (size_t)tileN * 2048, 2048, 2048,
              smem, acc);
  const int tid = threadIdx.x;
  const int wave = tid >> 6, lane = tid & 63;
  const int wr = wave >> 2, wc = wave & 3, fr = lane & 15, fg = lane >> 4;
  float* rs = (float*)smem;  // [4][256]; safe: core ends with full barrier
  u16* Po = P + (size_t)z * 4194304 + (size_t)tileM * 2048 + tileN;
#pragma unroll
  for (int mi = 0; mi < 8; ++mi) {
#pragma unroll
    for (int jj = 0; jj < 4; ++jj) {
      const int rl = wr * 128 + mi * 16 + fg * 4 + jj;
      float part = 0.f;
#pragma unroll
      for (int n = 0; n < 4; ++n) {
        float e = __expf(acc[mi * 4 + n][jj] * 0.03125f);
        part += e;
        Po[(size_t)rl * 2048 + wc * 64 + n * 16 + fr] = f2b(e);
      }
      part += __shfl_xor(part, 1);
      part += __shfl_xor(part, 2);
      part += __shfl_xor(part, 4);
      part += __shfl_xor(part, 8);
      if (fr == 0) rs[wc * 256 + rl] = part;
    }
  }
  __syncthreads();
  if (tid < 256) {
    float s = rs[tid] + rs[256 + tid] + rs[512 + tid] + rs[768 + tid];
    rowpart[(size_t)by * 8192 + z * 2048 + tileM + tid] = s;
  }
}

// ---------------- pv: core2g1; out = (P~ Vt^T) * rowinv ----------------
__global__ __launch_bounds__(512, 2) void pv8_kernel(const u16* __restrict__ P,
                                                     const u16* __restrict__ Vt,
                                                     const float* __restrict__ rowpart,
                                                     float* __restrict__ out) {
  extern __shared__ char smem[];  // 98304 core + 512 rowinv
  const int wk = xcd_swz(blockIdx.x);
  const int bx = wk & 15, by = (wk >> 4) & 3, z = wk >> 6;
  const int tileM = bx * 128, tileN = by * 256;
  float* rinv = (float*)(smem + 98304);
  const int tid = threadIdx.x;
  if (tid < 128) {
    float s = 0.f;
#pragma unroll
    for (int t = 0; t < 8; ++t) s += rowpart[t * 8192 + z * 2048 + tileM + tid];
    rinv[tid] = 1.0f / s;
  }
  __builtin_amdgcn_sched_barrier(0);
  f32x4 acc[16] = {};
  core2g1<32>((const char*)P + (size_t)z * 8388608 + (size_t)tileM * 4096,
              (const char*)Vt + (size_t)z * 4194304 + (size_t)tileN * 4096, 4096, 4096,
              smem, acc);
  const int wave = tid >> 6, lane = tid & 63;
  const int wr = wave >> 2, wc = wave & 3, fr = lane & 15, fg = lane >> 4;
  float* O = out + (size_t)z * 2097152;
#pragma unroll
  for (int mi = 0; mi < 4; ++mi) {
#pragma unroll
    for (int jj = 0; jj < 4; ++jj) {
      const int r = wr * 64 + mi * 16 + fg * 4 + jj;
      const float inv = rinv[r];
#pragma unroll
      for (int n = 0; n < 4; ++n)
        O[(size_t)(tileM + r) * 1024 + tileN + wc * 64 + n * 16 + fr] =
            acc[mi * 4 + n][jj] * inv;
    }
  }
}

extern "C" void kernel_launch(void* const* d_in, const int* in_sizes, int n_in,
                              void* d_out, int out_size, void* d_ws, size_t ws_size,
                              hipStream_t stream) {
  if (ws_size < ((size_t)72 << 20)) return;
  const float* x = (const float*)d_in[0];
  const float* Wq = (const float*)d_in[1];
  const float* bq = (const float*)d_in[2];
  const float* Wk = (const float*)d_in[3];
  const float* bk = (const float*)d_in[4];
  const float* Wv = (const float*)d_in[5];
  const float* bv = (const float*)d_in[6];
  char* ws = (char*)d_ws;
  u16* xb = (u16*)(ws);                       // [0,16M); later P~ [4][2048][2048]
  u16* Pb = (u16*)(ws);
  u16* Qb = (u16*)(ws + ((size_t)16 << 20));
  u16* Kb = (u16*)(ws + ((size_t)32 << 20));
  u16* Vt = (u16*)(ws + ((size_t)48 << 20));
  u16* Wb = (u16*)(ws + ((size_t)64 << 20));
  float* rowpart = (float*)(ws + ((size_t)70 << 20));  // 256 KiB
  float* out = (float*)d_out;

  (void)hipFuncSetAttribute((const void*)qkproj_kernel,
                            hipFuncAttributeMaxDynamicSharedMemorySize, 131072);
  (void)hipFuncSetAttribute((const void*)vproj_kernel,
                            hipFuncAttributeMaxDynamicSharedMemorySize, 98304);
  (void)hipFuncSetAttribute((const void*)sc8_kernel,
                            hipFuncAttributeMaxDynamicSharedMemorySize, 131072);
  (void)hipFuncSetAttribute((const void*)pv8_kernel,
                            hipFuncAttributeMaxDynamicSharedMemorySize, 98816);

  cast_all_kernel<<<11264, 256, 0, stream>>>(x, Wq, Wk, Wv, xb, Wb);

  qkproj_kernel<<<256, 512, 131072, stream>>>(xb, Wb, bq, bk, Qb);
  vproj_kernel<<<256, 512, 98304, stream>>>(xb, Wb + 2097152, bv, Vt);

  sc8_kernel<<<256, 512, 131072, stream>>>(Qb, Kb, Pb, rowpart);
  pv8_kernel<<<256, 512, 98816, stream>>>(Pb, Vt, rowpart, out);
}